// Round 5
// baseline (1076.102 us; speedup 1.0000x reference)
//
#include <hip/hip_runtime.h>
#include <stdint.h>

#define HW 262144          // 512*512
#define LDIM 33

typedef __bf16 bf16x8 __attribute__((ext_vector_type(8)));
typedef __bf16 bf16x2 __attribute__((ext_vector_type(2)));
typedef float  f32x4  __attribute__((ext_vector_type(4)));

union BF8 { bf16x8 v; unsigned u[4]; };

// native f32->bf16 (RNE) — compiler fuses pairs into v_cvt_pk_bf16_f32
__device__ __forceinline__ unsigned pk2(float a, float b) {
  bf16x2 p; p[0] = (__bf16)a; p[1] = (__bf16)b;
  return __builtin_bit_cast(unsigned, p);
}
__device__ __forceinline__ float tanh_fast(float x) {
  return 1.0f - 2.0f / (__expf(2.0f * x) + 1.0f);
}
__device__ __forceinline__ float gelu_t(float x) {
  float t = tanh_fast(0.7978845608028654f * (x + 0.044715f * x * x * x));
  return 0.5f * x * (1.0f + t);
}

// LDS map (65536 B total, 512 threads / 8 waves):
//   [0,     32768)  W1 bf16: 128 rows x 256B, 16B group kg stored at (kg ^ (row&15))
//   [32768, 49152)  W2 bf16:  64 rows x 256B, same swizzle
//   [49152, 65536)  per-wave h: 8 waves x 2048B (16 rows x 128B, group swizz kg^(row&7))
//                   offsets alias the h region (h dead by then), 12B/px.
// 16 px per wave-iter: matrix state = a1(16)+acc1(16)+acc2(16) = 48 VGPR (half of
// round-0's 32px tile which compiled to 88 total with a FREE budget). launch_bounds
// (512,2) keeps the free 256-reg budget = the proven NO-SPILL regime. If actual
// VGPR <= 128 the HW grants 4 waves/SIMD; LDS 64KB -> 2 blocks/CU -> 16 waves/CU.
// W1 AND W2 both in LDS (r4 showed W2-in-global thrashes L1 under ctx streaming
// and the hoisted fragments cost 32 VGPRs).
__global__ __launch_bounds__(512, 2) void local3dlut_kernel(
    const float* __restrict__ img,  const float* __restrict__ ctx,
    const float* __restrict__ lut,  const float* __restrict__ W1,
    const float* __restrict__ b1,   const float* __restrict__ W2,
    const float* __restrict__ b2,   const float* __restrict__ W3,
    const float* __restrict__ b3,   const float* __restrict__ oscp,
    float* __restrict__ out)
{
  __shared__ uint4 smem4[4096];
  char* sm = (char*)smem4;
  const int t    = threadIdx.x;
  const int lane = t & 63;
  const int wv   = t >> 6;        // wave 0..7
  const int n    = lane & 15;
  const int q    = lane >> 4;     // quad 0..3

  // ---- stage W1 (128x128) and W2 (64x128) to LDS as swizzled bf16 ----
  #pragma unroll
  for (int rep = 0; rep < 8; ++rep) {
    int f4 = t + 512 * rep;                 // float4 index 0..4095
    float4 v = ((const float4*)W1)[f4];
    int fi = f4 << 2;
    int o = fi >> 7, k = fi & 127;
    char* dst = sm + o * 256 + (((k >> 3) ^ (o & 15)) << 4) + ((k & 7) << 1);
    *(uint2*)dst = make_uint2(pk2(v.x, v.y), pk2(v.z, v.w));
  }
  #pragma unroll
  for (int rep = 0; rep < 4; ++rep) {
    int f4 = t + 512 * rep;                 // 0..2047
    float4 v = ((const float4*)W2)[f4];
    int fi = f4 << 2;
    int o = fi >> 7, k = fi & 127;
    char* dst = sm + 32768 + o * 256 + (((k >> 3) ^ (o & 15)) << 4) + ((k & 7) << 1);
    *(uint2*)dst = make_uint2(pk2(v.x, v.y), pk2(v.z, v.w));
  }
  __syncthreads();

  // per-lane constants
  float b1r[8], b2r[4], w3r[3][4];
  #pragma unroll
  for (int i = 0; i < 8; ++i) b1r[i] = b1[i * 16 + n];
  #pragma unroll
  for (int i = 0; i < 4; ++i) b2r[i] = b2[i * 16 + n];
  #pragma unroll
  for (int j = 0; j < 3; ++j)
    #pragma unroll
    for (int i = 0; i < 4; ++i) w3r[j][i] = W3[j * 64 + i * 16 + n];
  const float b3r0 = b3[0], b3r1 = b3[1], b3r2 = b3[2];
  const float osc  = oscp[0];

  const int p0   = blockIdx.x * 1024;       // 1024 px per block, never crosses batch b
  const int bi   = p0 >> 18;
  const int sblk = p0 & (HW - 1);
  const float* ctxB = ctx + (size_t)bi * ((size_t)128 * HW);
  const float* imgB = img + (size_t)bi * ((size_t)3 * HW);
  float*       outB = out + (size_t)bi * ((size_t)3 * HW);
  char* hb = sm + 49152 + wv * 2048;

  #pragma unroll 1
  for (int it = 0; it < 8; ++it) {
    const int sw = sblk + it * 128 + wv * 16;   // wave's 16-px base in image

    // hoist image loads: needed only in the tail, issue them now so the
    // HBM latency hides under the GEMMs (all quads duplicate px 0..15; each
    // lane ends up holding the img values for ITS tail pixel px = n)
    const int spf = sw + n;
    const float rr = imgB[spf];
    const float gg = imgB[HW + spf];
    const float bb = imgB[2 * HW + spf];

    // ---- A1 fragments: ctx, 4 ksteps (global, fragment order) ----
    BF8 a1[4];
    {
      const int sA = sw + n;
      #pragma unroll
      for (int ks = 0; ks < 4; ++ks) {
        const float* cb = ctxB + (size_t)(ks * 32 + q * 8) * HW + sA;
        float v0 = cb[0];
        float v1 = cb[(size_t)1 * HW];
        float v2 = cb[(size_t)2 * HW];
        float v3 = cb[(size_t)3 * HW];
        float v4 = cb[(size_t)4 * HW];
        float v5 = cb[(size_t)5 * HW];
        float v6 = cb[(size_t)6 * HW];
        float v7 = cb[(size_t)7 * HW];
        a1[ks].u[0] = pk2(v0, v1);
        a1[ks].u[1] = pk2(v2, v3);
        a1[ks].u[2] = pk2(v4, v5);
        a1[ks].u[3] = pk2(v6, v7);
      }
    }

    f32x4 acc2[4];
    #pragma unroll
    for (int j = 0; j < 4; ++j) { f32x4 z = {0.f,0.f,0.f,0.f}; acc2[j] = z; }

    #pragma unroll
    for (int half = 0; half < 2; ++half) {
      // ---- GEMM1 over 4 ntiles of this half ----
      f32x4 acc1[4];
      #pragma unroll
      for (int j = 0; j < 4; ++j) { f32x4 z = {0.f,0.f,0.f,0.f}; acc1[j] = z; }

      #pragma unroll
      for (int ks = 0; ks < 4; ++ks) {
        #pragma unroll
        for (int nt4 = 0; nt4 < 4; ++nt4) {
          int row = (half * 4 + nt4) * 16 + n;
          bf16x8 bw = *(const bf16x8*)(sm + row * 256 + ((((ks << 2) + q) ^ n) << 4));
          acc1[nt4] = __builtin_amdgcn_mfma_f32_16x16x32_bf16(a1[ks].v, bw, acc1[nt4], 0, 0, 0);
        }
      }
      // ---- h1 half: bias + gelu -> bf16 -> LDS (C/D -> A layout transpose) ----
      #pragma unroll
      for (int nt4 = 0; nt4 < 4; ++nt4) {
        int fl = nt4 * 16 + n;          // feature within half, 0..63
        int kgf = fl >> 3;
        #pragma unroll
        for (int r = 0; r < 4; ++r) {
          int px = (q << 2) + r;        // 0..15
          float hv = gelu_t(acc1[nt4][r] + b1r[half * 4 + nt4]);
          *(__bf16*)(hb + px * 128 + ((kgf ^ (px & 7)) << 4) + ((fl & 7) << 1)) = (__bf16)hv;
        }
      }
      // ---- GEMM2 partial over this half's 64 features ----
      #pragma unroll
      for (int ks2 = 0; ks2 < 2; ++ks2) {
        bf16x8 a2 = *(const bf16x8*)(hb + n * 128 + ((((ks2 << 2) + q) ^ (n & 7)) << 4));
        #pragma unroll
        for (int nt2 = 0; nt2 < 4; ++nt2) {
          int row = nt2 * 16 + n;
          int kg2 = half * 8 + (ks2 << 2) + q;
          bf16x8 bw = *(const bf16x8*)(sm + 32768 + row * 256 + ((kg2 ^ n) << 4));
          acc2[nt2] = __builtin_amdgcn_mfma_f32_16x16x32_bf16(a2, bw, acc2[nt2], 0, 0, 0);
        }
      }
    }

    // ---- h2 = gelu(acc2 + b2) in-place; layer3 dot + 16-lane reduce; offsets -> LDS ----
    #pragma unroll
    for (int nt2 = 0; nt2 < 4; ++nt2)
      #pragma unroll
      for (int r = 0; r < 4; ++r)
        acc2[nt2][r] = gelu_t(acc2[nt2][r] + b2r[nt2]);

    #pragma unroll
    for (int r = 0; r < 4; ++r) {
      float h0 = acc2[0][r], h1v = acc2[1][r], h2v = acc2[2][r], h3v = acc2[3][r];
      float pa = w3r[0][0]*h0 + w3r[0][1]*h1v + w3r[0][2]*h2v + w3r[0][3]*h3v;
      float pb = w3r[1][0]*h0 + w3r[1][1]*h1v + w3r[1][2]*h2v + w3r[1][3]*h3v;
      float pc = w3r[2][0]*h0 + w3r[2][1]*h1v + w3r[2][2]*h2v + w3r[2][3]*h3v;
      pa += __shfl_xor(pa, 1, 16); pa += __shfl_xor(pa, 2, 16);
      pa += __shfl_xor(pa, 4, 16); pa += __shfl_xor(pa, 8, 16);
      pb += __shfl_xor(pb, 1, 16); pb += __shfl_xor(pb, 2, 16);
      pb += __shfl_xor(pb, 4, 16); pb += __shfl_xor(pb, 8, 16);
      pc += __shfl_xor(pc, 1, 16); pc += __shfl_xor(pc, 2, 16);
      pc += __shfl_xor(pc, 4, 16); pc += __shfl_xor(pc, 8, 16);
      int px = (q << 2) + r;
      float sel  = (n == 0) ? pa   : ((n == 1) ? pb   : pc);
      float bsel = (n == 0) ? b3r0 : ((n == 1) ? b3r1 : b3r2);
      float ov = tanh_fast(sel + bsel) * osc;
      if (n < 3) *(float*)(hb + px * 12 + (n << 2)) = ov;   // h region dead here
    }

    // ---- final phase: LUT sample + store, 48 lanes: lane = ch*16 + px ----
    // (3x more tail parallelism than the old 16-lane version; per-lane scalar
    //  trilinear on one channel; ch-segment stores coalesce into one instr)
    {
      const int ch = q;               // quad 0,1,2 = channel; quad 3 idle
      const int sp = sw + n;          // this lane's pixel (img vals rr/gg/bb match)
      float gx = fminf(fmaxf((rr + 1.f) * 0.5f, 0.f), 1.f) * 32.f;  // R -> x (b axis)
      float gy = fminf(fmaxf((gg + 1.f) * 0.5f, 0.f), 1.f) * 32.f;  // G -> y (g axis)
      float gz = fminf(fmaxf((bb + 1.f) * 0.5f, 0.f), 1.f) * 32.f;  // B -> z (r axis)
      int x0 = (int)gx, y0 = (int)gy, z0 = (int)gz;
      float fx = gx - (float)x0, fy = gy - (float)y0, fz = gz - (float)z0;
      int x1 = min(x0 + 1, 32), y1 = min(y0 + 1, 32), z1 = min(z0 + 1, 32);
      int zy00 = (z0 * LDIM + y0) * LDIM, zy01 = (z0 * LDIM + y1) * LDIM;
      int zy10 = (z1 * LDIM + y0) * LDIM, zy11 = (z1 * LDIM + y1) * LDIM;
      if (lane < 48) {
        float ov = *(const float*)(hb + n * 12 + (ch << 2));
        const float* L = lut;
        float c000 = L[(zy00 + x0) * 3 + ch], c001 = L[(zy00 + x1) * 3 + ch];
        float c010 = L[(zy01 + x0) * 3 + ch], c011 = L[(zy01 + x1) * 3 + ch];
        float c100 = L[(zy10 + x0) * 3 + ch], c101 = L[(zy10 + x1) * 3 + ch];
        float c110 = L[(zy11 + x0) * 3 + ch], c111 = L[(zy11 + x1) * 3 + ch];
        float c00 = c000 + fx * (c001 - c000);
        float c01 = c010 + fx * (c011 - c010);
        float c10 = c100 + fx * (c101 - c100);
        float c11 = c110 + fx * (c111 - c110);
        float ca  = c00 + fy * (c01 - c00);
        float cb2 = c10 + fy * (c11 - c10);
        float so  = ca + fz * (cb2 - ca);
        outB[ch * HW + sp] = so * 2.f - 1.f + ov;
      }
    }
  }
}

extern "C" void kernel_launch(void* const* d_in, const int* in_sizes, int n_in,
                              void* d_out, int out_size, void* d_ws, size_t ws_size,
                              hipStream_t stream) {
  const float* img = (const float*)d_in[0];
  const float* ctx = (const float*)d_in[1];
  const float* lut = (const float*)d_in[2];
  const float* W1  = (const float*)d_in[3];
  const float* b1  = (const float*)d_in[4];
  const float* W2  = (const float*)d_in[5];
  const float* b2  = (const float*)d_in[6];
  const float* W3  = (const float*)d_in[7];
  const float* b3  = (const float*)d_in[8];
  const float* osc = (const float*)d_in[9];
  float* out = (float*)d_out;
  // 1024 blocks x 1024 px; 512 threads (8 waves), 64 KB LDS -> 2 blocks/CU;
  // VGPR target <=128 -> 16 waves/CU
  local3dlut_kernel<<<dim3(1024), dim3(512), 0, stream>>>(
      img, ctx, lut, W1, b1, W2, b2, W3, b3, osc, out);
}

// Round 6
// 788.257 us; speedup vs baseline: 1.3652x; 1.3652x over previous
//
#include <hip/hip_runtime.h>
#include <stdint.h>

#define HW 262144          // 512*512
#define LDIM 33

typedef __bf16 bf16x8 __attribute__((ext_vector_type(8)));
typedef __bf16 bf16x2 __attribute__((ext_vector_type(2)));
typedef float  f32x4  __attribute__((ext_vector_type(4)));

union BF8 { bf16x8 v; unsigned u[4]; };

// native f32->bf16 (RNE) — compiler fuses pairs into v_cvt_pk_bf16_f32
__device__ __forceinline__ unsigned pk2(float a, float b) {
  bf16x2 p; p[0] = (__bf16)a; p[1] = (__bf16)b;
  return __builtin_bit_cast(unsigned, p);
}
__device__ __forceinline__ float tanh_fast(float x) {
  return 1.0f - __fdividef(2.0f, __expf(2.0f * x) + 1.0f);
}
// gelu_tanh(x) = 0.5x(1+tanh(u)) == x - x/(e^{2u}+1), u = 0.79788456(x+0.044715x^3)
// 2u = 1.5957691x + 0.0713548x^3  (exact algebraic rewrite of the old form)
__device__ __forceinline__ float gelu_t(float x) {
  float x2 = x * x;
  float p  = x * fmaf(0.0713548163f, x2, 1.5957691216f);   // 2u
  float r  = __fdividef(1.0f, __expf(p) + 1.0f);           // sigmoid(-2u)
  return fmaf(-x, r, x);                                    // x(1 - r)
}

// LDS map (65536 B total, 256 threads / 4 waves — the r0 no-spill chassis):
//   [0,     32768)  W1 bf16: 128 rows x 256B, 16B group kg stored at (kg ^ (row&15))
//   [32768, 49152)  W2 bf16:  64 rows x 256B, same swizzle
//   [49152, 65536)  per-wave h1: 4 waves x 4096B (32 rows x 128B, group swizz kg^(row&7))
// No offset staging anymore: GEMM2 is operand-SWAPPED (mfma(W2,h1)) so acc2 has
// px on columns (=n) -> layer-3 is a per-lane dot + 2 wide shuffles, and the
// tail's offsets are already in the lanes that consume them.
// launch_bounds(256,2): free 256-reg budget = the proven NO-SPILL regime (r0: 88).
// Occupancy is LDS-capped (2 blocks/CU) -> the +~60 VGPRs of per-lane W3/b2
// constants are free.
__global__ __launch_bounds__(256, 2) void local3dlut_kernel(
    const float* __restrict__ img,  const float* __restrict__ ctx,
    const float* __restrict__ lut,  const float* __restrict__ W1,
    const float* __restrict__ b1,   const float* __restrict__ W2,
    const float* __restrict__ b2,   const float* __restrict__ W3,
    const float* __restrict__ b3,   const float* __restrict__ oscp,
    float* __restrict__ out)
{
  __shared__ uint4 smem4[4096];
  char* sm = (char*)smem4;
  const int t    = threadIdx.x;
  const int lane = t & 63;
  const int wv   = t >> 6;        // wave 0..3
  const int n    = lane & 15;
  const int q    = lane >> 4;     // quad 0..3

  // ---- stage W1 (128x128) and W2 (64x128) to LDS as swizzled bf16 ----
  #pragma unroll
  for (int rep = 0; rep < 16; ++rep) {
    int f4 = t + 256 * rep;                 // float4 index 0..4095
    float4 v = ((const float4*)W1)[f4];
    int fi = f4 << 2;
    int o = fi >> 7, k = fi & 127;
    char* dst = sm + o * 256 + (((k >> 3) ^ (o & 15)) << 4) + ((k & 7) << 1);
    *(uint2*)dst = make_uint2(pk2(v.x, v.y), pk2(v.z, v.w));
  }
  #pragma unroll
  for (int rep = 0; rep < 8; ++rep) {
    int f4 = t + 256 * rep;                 // 0..2047
    float4 v = ((const float4*)W2)[f4];
    int fi = f4 << 2;
    int o = fi >> 7, k = fi & 127;
    char* dst = sm + 32768 + o * 256 + (((k >> 3) ^ (o & 15)) << 4) + ((k & 7) << 1);
    *(uint2*)dst = make_uint2(pk2(v.x, v.y), pk2(v.z, v.w));
  }
  __syncthreads();

  // per-lane constants
  float b1r[8];                       // b1[feature], feature col = n
  #pragma unroll
  for (int i = 0; i < 8; ++i) b1r[i] = b1[i * 16 + n];
  float b2l[4][4];                    // b2[nt2*16 + q*4 + r]  (swapped acc2 rows)
  #pragma unroll
  for (int i = 0; i < 4; ++i)
    #pragma unroll
    for (int r = 0; r < 4; ++r) b2l[i][r] = b2[i * 16 + (q << 2) + r];
  float w3l[3][4][4];                 // W3[ch][nt2*16 + q*4 + r]
  #pragma unroll
  for (int c = 0; c < 3; ++c)
    #pragma unroll
    for (int i = 0; i < 4; ++i)
      #pragma unroll
      for (int r = 0; r < 4; ++r) w3l[c][i][r] = W3[c * 64 + i * 16 + (q << 2) + r];
  const float b3a0 = b3[0], b3a1 = b3[1], b3a2 = b3[2];
  const float osc  = oscp[0];

  const int p0   = blockIdx.x * 512;        // 512 px per block, never crosses batch b
  const int bi   = p0 >> 18;
  const int sblk = p0 & (HW - 1);
  const float* ctxB = ctx + (size_t)bi * ((size_t)128 * HW);
  const float* imgB = img + (size_t)bi * ((size_t)3 * HW);
  float*       outB = out + (size_t)bi * ((size_t)3 * HW);
  char* hb = sm + 49152 + wv * 4096;

  #pragma unroll 1
  for (int it = 0; it < 4; ++it) {
    const int sw = sblk + it * 128 + wv * 32;   // wave's 32-px base in image

    // img loads for BOTH tail pixels of this lane (px = n and 16+n), hoisted so
    // HBM latency hides under the GEMMs
    const float ri0 = imgB[sw + n];
    const float gi0 = imgB[HW + sw + n];
    const float bi0 = imgB[2 * HW + sw + n];
    const float ri1 = imgB[sw + 16 + n];
    const float gi1 = imgB[HW + sw + 16 + n];
    const float bi1 = imgB[2 * HW + sw + 16 + n];

    // ---- A1 fragments: ctx, 2 mtiles x 4 ksteps (global, fragment order) ----
    BF8 a1[2][4];
    #pragma unroll
    for (int mt = 0; mt < 2; ++mt) {
      const int sA = sw + mt * 16 + n;
      #pragma unroll
      for (int ks = 0; ks < 4; ++ks) {
        const float* cb = ctxB + (size_t)(ks * 32 + q * 8) * HW + sA;
        float v0 = cb[0];
        float v1 = cb[(size_t)1 * HW];
        float v2 = cb[(size_t)2 * HW];
        float v3 = cb[(size_t)3 * HW];
        float v4 = cb[(size_t)4 * HW];
        float v5 = cb[(size_t)5 * HW];
        float v6 = cb[(size_t)6 * HW];
        float v7 = cb[(size_t)7 * HW];
        a1[mt][ks].u[0] = pk2(v0, v1);
        a1[mt][ks].u[1] = pk2(v2, v3);
        a1[mt][ks].u[2] = pk2(v4, v5);
        a1[mt][ks].u[3] = pk2(v6, v7);
      }
    }

    f32x4 acc2[2][4];
    #pragma unroll
    for (int mt = 0; mt < 2; ++mt)
      #pragma unroll
      for (int j = 0; j < 4; ++j) { f32x4 z = {0.f,0.f,0.f,0.f}; acc2[mt][j] = z; }

    #pragma unroll
    for (int half = 0; half < 2; ++half) {
      // ---- GEMM1 over 4 ntiles of this half (unswapped: D[px][feat]) ----
      f32x4 acc1[2][4];
      #pragma unroll
      for (int mt = 0; mt < 2; ++mt)
        #pragma unroll
        for (int j = 0; j < 4; ++j) { f32x4 z = {0.f,0.f,0.f,0.f}; acc1[mt][j] = z; }

      #pragma unroll
      for (int ks = 0; ks < 4; ++ks) {
        #pragma unroll
        for (int nt4 = 0; nt4 < 4; ++nt4) {
          int row = (half * 4 + nt4) * 16 + n;
          bf16x8 bw = *(const bf16x8*)(sm + row * 256 + ((((ks << 2) + q) ^ n) << 4));
          acc1[0][nt4] = __builtin_amdgcn_mfma_f32_16x16x32_bf16(a1[0][ks].v, bw, acc1[0][nt4], 0, 0, 0);
          acc1[1][nt4] = __builtin_amdgcn_mfma_f32_16x16x32_bf16(a1[1][ks].v, bw, acc1[1][nt4], 0, 0, 0);
        }
      }
      // ---- h1 half: bias + gelu -> bf16 -> LDS (C/D -> fragment transpose) ----
      #pragma unroll
      for (int mt = 0; mt < 2; ++mt)
        #pragma unroll
        for (int nt4 = 0; nt4 < 4; ++nt4) {
          int fl = nt4 * 16 + n;        // feature within half, 0..63
          int kgf = fl >> 3;
          #pragma unroll
          for (int r = 0; r < 4; ++r) {
            int px = mt * 16 + (q << 2) + r;
            float hv = gelu_t(acc1[mt][nt4][r] + b1r[half * 4 + nt4]);
            *(__bf16*)(hb + px * 128 + ((kgf ^ (px & 7)) << 4) + ((fl & 7) << 1)) = (__bf16)hv;
          }
        }
      // ---- GEMM2 partial, operand-SWAPPED: acc2 = W2·h1^T -> D[feat2][px] ----
      // W2 LDS read pattern doubles as the A-fragment; h1 read doubles as B.
      #pragma unroll
      for (int ks2 = 0; ks2 < 2; ++ks2) {
        bf16x8 a2[2];
        #pragma unroll
        for (int mt = 0; mt < 2; ++mt) {
          int px = mt * 16 + n;
          a2[mt] = *(const bf16x8*)(hb + px * 128 + ((((ks2 << 2) + q) ^ (px & 7)) << 4));
        }
        #pragma unroll
        for (int nt2 = 0; nt2 < 4; ++nt2) {
          int row = nt2 * 16 + n;
          int kg2 = half * 8 + (ks2 << 2) + q;
          bf16x8 bw = *(const bf16x8*)(sm + 32768 + row * 256 + ((kg2 ^ n) << 4));
          acc2[0][nt2] = __builtin_amdgcn_mfma_f32_16x16x32_bf16(bw, a2[0], acc2[0][nt2], 0, 0, 0);
          acc2[1][nt2] = __builtin_amdgcn_mfma_f32_16x16x32_bf16(bw, a2[1], acc2[1][nt2], 0, 0, 0);
        }
      }
    }

    // ---- h2 = gelu(acc2 + b2): acc2[mt][nt2][r] = (feature2 = nt2*16+q*4+r, px = mt*16+n)
    #pragma unroll
    for (int mt = 0; mt < 2; ++mt)
      #pragma unroll
      for (int nt2 = 0; nt2 < 4; ++nt2)
        #pragma unroll
        for (int r = 0; r < 4; ++r)
          acc2[mt][nt2][r] = gelu_t(acc2[mt][nt2][r] + b2l[nt2][r]);

    // ---- layer3: per-lane partial dot over this lane's 16 features, then
    //      butterfly across quads (xor 16, 32). All quads end with the sums. ----
    float o0[3], o1[3];
    #pragma unroll
    for (int ch = 0; ch < 3; ++ch) {
      float s0 = 0.f, s1 = 0.f;
      #pragma unroll
      for (int nt2 = 0; nt2 < 4; ++nt2)
        #pragma unroll
        for (int r = 0; r < 4; ++r) {
          s0 = fmaf(w3l[ch][nt2][r], acc2[0][nt2][r], s0);
          s1 = fmaf(w3l[ch][nt2][r], acc2[1][nt2][r], s1);
        }
      s0 += __shfl_xor(s0, 16); s0 += __shfl_xor(s0, 32);
      s1 += __shfl_xor(s1, 16); s1 += __shfl_xor(s1, 32);
      float bch = (ch == 0) ? b3a0 : ((ch == 1) ? b3a1 : b3a2);
      o0[ch] = tanh_fast(s0 + bch) * osc;
      o1[ch] = tanh_fast(s1 + bch) * osc;
    }

    // ---- tail: 48 lanes, ch = q (q<3), px = n (mt0) and 16+n (mt1);
    //      offsets are already in-register, no LDS traffic ----
    if (q < 3) {
      const float ov0 = (q == 0) ? o0[0] : ((q == 1) ? o0[1] : o0[2]);
      const float ov1 = (q == 0) ? o1[0] : ((q == 1) ? o1[1] : o1[2]);
      const float* L = lut;
      #pragma unroll
      for (int mt = 0; mt < 2; ++mt) {
        const float rr = mt ? ri1 : ri0;
        const float gg = mt ? gi1 : gi0;
        const float bb = mt ? bi1 : bi0;
        const float ov = mt ? ov1 : ov0;
        const int sp = sw + mt * 16 + n;
        float gx = fminf(fmaxf((rr + 1.f) * 0.5f, 0.f), 1.f) * 32.f;  // R -> x (b axis)
        float gy = fminf(fmaxf((gg + 1.f) * 0.5f, 0.f), 1.f) * 32.f;  // G -> y (g axis)
        float gz = fminf(fmaxf((bb + 1.f) * 0.5f, 0.f), 1.f) * 32.f;  // B -> z (r axis)
        int x0 = (int)gx, y0 = (int)gy, z0 = (int)gz;
        float fx = gx - (float)x0, fy = gy - (float)y0, fz = gz - (float)z0;
        int x1 = min(x0 + 1, 32), y1 = min(y0 + 1, 32), z1 = min(z0 + 1, 32);
        int zy00 = (z0 * LDIM + y0) * LDIM, zy01 = (z0 * LDIM + y1) * LDIM;
        int zy10 = (z1 * LDIM + y0) * LDIM, zy11 = (z1 * LDIM + y1) * LDIM;
        float c000 = L[(zy00 + x0) * 3 + q], c001 = L[(zy00 + x1) * 3 + q];
        float c010 = L[(zy01 + x0) * 3 + q], c011 = L[(zy01 + x1) * 3 + q];
        float c100 = L[(zy10 + x0) * 3 + q], c101 = L[(zy10 + x1) * 3 + q];
        float c110 = L[(zy11 + x0) * 3 + q], c111 = L[(zy11 + x1) * 3 + q];
        float c00 = c000 + fx * (c001 - c000);
        float c01 = c010 + fx * (c011 - c010);
        float c10 = c100 + fx * (c101 - c100);
        float c11 = c110 + fx * (c111 - c110);
        float ca  = c00 + fy * (c01 - c00);
        float cb2 = c10 + fy * (c11 - c10);
        float so  = ca + fz * (cb2 - ca);
        outB[q * HW + sp] = so * 2.f - 1.f + ov;
      }
    }
  }
}

extern "C" void kernel_launch(void* const* d_in, const int* in_sizes, int n_in,
                              void* d_out, int out_size, void* d_ws, size_t ws_size,
                              hipStream_t stream) {
  const float* img = (const float*)d_in[0];
  const float* ctx = (const float*)d_in[1];
  const float* lut = (const float*)d_in[2];
  const float* W1  = (const float*)d_in[3];
  const float* b1  = (const float*)d_in[4];
  const float* W2  = (const float*)d_in[5];
  const float* b2  = (const float*)d_in[6];
  const float* W3  = (const float*)d_in[7];
  const float* b3  = (const float*)d_in[8];
  const float* osc = (const float*)d_in[9];
  float* out = (float*)d_out;
  // 2048 blocks x 512 px; 256 threads (4 waves), 64 KB LDS, 2 blocks/CU
  local3dlut_kernel<<<dim3(2048), dim3(256), 0, stream>>>(
      img, ctx, lut, W1, b1, W2, b2, W3, b3, osc, out);
}

// Round 7
// 770.878 us; speedup vs baseline: 1.3959x; 1.0225x over previous
//
#include <hip/hip_runtime.h>
#include <stdint.h>

#define HW 262144          // 512*512
#define LDIM 33

typedef __bf16 bf16x8 __attribute__((ext_vector_type(8)));
typedef __bf16 bf16x2 __attribute__((ext_vector_type(2)));
typedef float  f32x4  __attribute__((ext_vector_type(4)));

union BF8 { bf16x8 v; unsigned u[4]; };

// native f32->bf16 (RNE) — compiler fuses pairs into v_cvt_pk_bf16_f32
__device__ __forceinline__ unsigned pk2(float a, float b) {
  bf16x2 p; p[0] = (__bf16)a; p[1] = (__bf16)b;
  return __builtin_bit_cast(unsigned, p);
}
__device__ __forceinline__ float tanh_fast(float x) {
  return 1.0f - __fdividef(2.0f, __expf(2.0f * x) + 1.0f);
}
// gelu_tanh(x) = 0.5x(1+tanh(u)) == x - x/(e^{2u}+1); 2u = 1.5957691x + 0.0713548x^3
__device__ __forceinline__ float gelu_t(float x) {
  float x2 = x * x;
  float p  = x * fmaf(0.0713548163f, x2, 1.5957691216f);   // 2u
  float r  = __fdividef(1.0f, __expf(p) + 1.0f);           // sigmoid(-2u)
  return fmaf(-x, r, x);                                    // x(1 - r)
}

// LDS map (65536 B, 512 threads / 8 waves):
//   [0,     32768)  W1 bf16: 128 rows x 256B, 16B group kg stored at (kg ^ (row&15))
//   [32768, 49152)  W2 bf16:  64 rows x 256B, same swizzle
//   [49152, 65536)  per-wave h: 8 waves x 2048B (16 rows x 128B, group swizz kg^(row&7))
//                   holds h1 per half, then h2 for the layer-3 MFMA (wave-local reuse)
// 16 px per wave-iter. Live set: a1(16)+acc1(16)+acc2(16)+acc3(4)+w3a(8)+b1r(8)
// +b2r(4)+img(3)+temps ~= 100-110 total (arch+acc) -> fits the forced 128 budget of
// launch_bounds(512,4) with NO spill (r1/r3/r5 spilled at ~140+ live; this body was
// restructured to delete w3l(48)+b2l(16) and halve the matrix state).
// Occupancy: VGPR<=128 -> 4 waves/SIMD; LDS 64KB -> 2 blocks/CU -> 16 waves/CU.
__global__ __launch_bounds__(512, 4) void local3dlut_kernel(
    const float* __restrict__ img,  const float* __restrict__ ctx,
    const float* __restrict__ lut,  const float* __restrict__ W1,
    const float* __restrict__ b1,   const float* __restrict__ W2,
    const float* __restrict__ b2,   const float* __restrict__ W3,
    const float* __restrict__ b3,   const float* __restrict__ oscp,
    float* __restrict__ out)
{
  __shared__ uint4 smem4[4096];
  char* sm = (char*)smem4;
  const int t    = threadIdx.x;
  const int lane = t & 63;
  const int wv   = t >> 6;        // wave 0..7
  const int n    = lane & 15;
  const int q    = lane >> 4;     // quad 0..3

  // ---- stage W1 (128x128) and W2 (64x128) to LDS as swizzled bf16 ----
  #pragma unroll
  for (int rep = 0; rep < 8; ++rep) {
    int f4 = t + 512 * rep;                 // float4 index 0..4095
    float4 v = ((const float4*)W1)[f4];
    int fi = f4 << 2;
    int o = fi >> 7, k = fi & 127;
    char* dst = sm + o * 256 + (((k >> 3) ^ (o & 15)) << 4) + ((k & 7) << 1);
    *(uint2*)dst = make_uint2(pk2(v.x, v.y), pk2(v.z, v.w));
  }
  #pragma unroll
  for (int rep = 0; rep < 4; ++rep) {
    int f4 = t + 512 * rep;                 // 0..2047
    float4 v = ((const float4*)W2)[f4];
    int fi = f4 << 2;
    int o = fi >> 7, k = fi & 127;
    char* dst = sm + 32768 + o * 256 + (((k >> 3) ^ (o & 15)) << 4) + ((k & 7) << 1);
    *(uint2*)dst = make_uint2(pk2(v.x, v.y), pk2(v.z, v.w));
  }
  __syncthreads();

  // per-lane constants
  float b1r[8];                       // b1[half*4+nt4 feature blocks], col = n
  #pragma unroll
  for (int i = 0; i < 8; ++i) b1r[i] = b1[i * 16 + n];
  float b2r[4];                       // b2[nt2*16 + n] (unswapped acc2 cols = feat2)
  #pragma unroll
  for (int i = 0; i < 4; ++i) b2r[i] = b2[i * 16 + n];
  // W3 padded 16x64 as a permanent A-fragment pair (rows 3..15 zero): lane (n,q)
  // holds A[row=n][k = ks3*32 + q*8 + j], j=0..7
  BF8 w3a[2];
  #pragma unroll
  for (int ks3 = 0; ks3 < 2; ++ks3) {
    #pragma unroll
    for (int m = 0; m < 4; ++m) {
      float e0 = 0.f, e1 = 0.f;
      if (n < 3) {
        e0 = W3[n * 64 + ks3 * 32 + q * 8 + 2 * m];
        e1 = W3[n * 64 + ks3 * 32 + q * 8 + 2 * m + 1];
      }
      w3a[ks3].u[m] = pk2(e0, e1);
    }
  }
  const float b3a0 = b3[0], b3a1 = b3[1], b3a2 = b3[2];
  const float osc  = oscp[0];

  const int p0   = blockIdx.x * 1024;       // 1024 px per block, never crosses batch b
  const int bi   = p0 >> 18;
  const int sblk = p0 & (HW - 1);
  const float* ctxB = ctx + (size_t)bi * ((size_t)128 * HW);
  const float* imgB = img + (size_t)bi * ((size_t)3 * HW);
  float*       outB = out + (size_t)bi * ((size_t)3 * HW);
  char* hb = sm + 49152 + wv * 2048;

  #pragma unroll 1
  for (int it = 0; it < 8; ++it) {
    const int sw = sblk + it * 128 + wv * 16;   // wave's 16-px base in image

    // img loads for this lane's tail pixel (px = n), hoisted under the GEMMs
    const int spf = sw + n;
    const float rr = imgB[spf];
    const float gg = imgB[HW + spf];
    const float bb = imgB[2 * HW + spf];

    // ---- A1 fragments: ctx, 4 ksteps (global, fragment order) ----
    BF8 a1[4];
    {
      const int sA = sw + n;
      #pragma unroll
      for (int ks = 0; ks < 4; ++ks) {
        const float* cb = ctxB + (size_t)(ks * 32 + q * 8) * HW + sA;
        float v0 = cb[0];
        float v1 = cb[(size_t)1 * HW];
        float v2 = cb[(size_t)2 * HW];
        float v3 = cb[(size_t)3 * HW];
        float v4 = cb[(size_t)4 * HW];
        float v5 = cb[(size_t)5 * HW];
        float v6 = cb[(size_t)6 * HW];
        float v7 = cb[(size_t)7 * HW];
        a1[ks].u[0] = pk2(v0, v1);
        a1[ks].u[1] = pk2(v2, v3);
        a1[ks].u[2] = pk2(v4, v5);
        a1[ks].u[3] = pk2(v6, v7);
      }
    }

    f32x4 acc2[4];
    #pragma unroll
    for (int j = 0; j < 4; ++j) { f32x4 z = {0.f,0.f,0.f,0.f}; acc2[j] = z; }

    #pragma unroll
    for (int half = 0; half < 2; ++half) {
      // ---- GEMM1 over 4 ntiles of this half (D[px][feat]) ----
      f32x4 acc1[4];
      #pragma unroll
      for (int j = 0; j < 4; ++j) { f32x4 z = {0.f,0.f,0.f,0.f}; acc1[j] = z; }

      #pragma unroll
      for (int ks = 0; ks < 4; ++ks) {
        #pragma unroll
        for (int nt4 = 0; nt4 < 4; ++nt4) {
          int row = (half * 4 + nt4) * 16 + n;
          bf16x8 bw = *(const bf16x8*)(sm + row * 256 + ((((ks << 2) + q) ^ n) << 4));
          acc1[nt4] = __builtin_amdgcn_mfma_f32_16x16x32_bf16(a1[ks].v, bw, acc1[nt4], 0, 0, 0);
        }
      }
      // ---- h1 half: bias + gelu -> bf16 -> LDS (C/D -> A-fragment transpose) ----
      #pragma unroll
      for (int nt4 = 0; nt4 < 4; ++nt4) {
        int fl = nt4 * 16 + n;          // feature within half, 0..63
        int kgf = fl >> 3;
        #pragma unroll
        for (int r = 0; r < 4; ++r) {
          int px = (q << 2) + r;        // 0..15
          float hv = gelu_t(acc1[nt4][r] + b1r[half * 4 + nt4]);
          *(__bf16*)(hb + px * 128 + ((kgf ^ (px & 7)) << 4) + ((fl & 7) << 1)) = (__bf16)hv;
        }
      }
      // ---- GEMM2 partial (unswapped: D[px][feat2]) over this half's 64 feats ----
      #pragma unroll
      for (int ks2 = 0; ks2 < 2; ++ks2) {
        bf16x8 a2 = *(const bf16x8*)(hb + n * 128 + ((((ks2 << 2) + q) ^ (n & 7)) << 4));
        #pragma unroll
        for (int nt2 = 0; nt2 < 4; ++nt2) {
          int row = nt2 * 16 + n;
          int kg2 = half * 8 + (ks2 << 2) + q;
          bf16x8 bw = *(const bf16x8*)(sm + 32768 + row * 256 + ((kg2 ^ n) << 4));
          acc2[nt2] = __builtin_amdgcn_mfma_f32_16x16x32_bf16(a2, bw, acc2[nt2], 0, 0, 0);
        }
      }
    }

    // ---- h2 = gelu(acc2 + b2) -> bf16 -> LDS [px][feat2] (swizzled) ----
    // lane holds h2[px = q*4+r][feat2 = nt2*16+n]
    #pragma unroll
    for (int nt2 = 0; nt2 < 4; ++nt2) {
      int kgW = (nt2 << 1) + (n >> 3);
      #pragma unroll
      for (int r = 0; r < 4; ++r) {
        int px = (q << 2) + r;
        float hv = gelu_t(acc2[nt2][r] + b2r[nt2]);
        *(__bf16*)(hb + px * 128 + ((kgW ^ (px & 7)) << 4) + ((n & 7) << 1)) = (__bf16)hv;
      }
    }

    // ---- GEMM3: D[ch][px] = W3pad(16x64) x h2^T ; B-frag: lane (n,q) reads
    //      feats ks3*32+q*8..+7 at px = n ----
    f32x4 acc3 = {0.f, 0.f, 0.f, 0.f};
    #pragma unroll
    for (int ks3 = 0; ks3 < 2; ++ks3) {
      bf16x8 hf = *(const bf16x8*)(hb + n * 128 + ((((ks3 << 2) + q) ^ (n & 7)) << 4));
      acc3 = __builtin_amdgcn_mfma_f32_16x16x32_bf16(w3a[ks3].v, hf, acc3, 0, 0, 0);
    }
    // rows q*4+r: q=0,r=0..2 hold ch 0..2 for px=n. Redistribute so lane (n, q<3)
    // gets ch=q via 3 bpermutes from lane n (q=0).
    const int ba = n << 2;
    float d0 = __int_as_float(__builtin_amdgcn_ds_bpermute(ba, __float_as_int(acc3[0])));
    float d1 = __int_as_float(__builtin_amdgcn_ds_bpermute(ba, __float_as_int(acc3[1])));
    float d2 = __int_as_float(__builtin_amdgcn_ds_bpermute(ba, __float_as_int(acc3[2])));

    // ---- tail: 48 lanes, ch = q (q<3), px = n; offset in-register ----
    if (q < 3) {
      float sel  = (q == 0) ? d0   : ((q == 1) ? d1   : d2);
      float bsel = (q == 0) ? b3a0 : ((q == 1) ? b3a1 : b3a2);
      float ov = tanh_fast(sel + bsel) * osc;

      const int sp = sw + n;
      float gx = fminf(fmaxf((rr + 1.f) * 0.5f, 0.f), 1.f) * 32.f;  // R -> x (b axis)
      float gy = fminf(fmaxf((gg + 1.f) * 0.5f, 0.f), 1.f) * 32.f;  // G -> y (g axis)
      float gz = fminf(fmaxf((bb + 1.f) * 0.5f, 0.f), 1.f) * 32.f;  // B -> z (r axis)
      int x0 = (int)gx, y0 = (int)gy, z0 = (int)gz;
      float fx = gx - (float)x0, fy = gy - (float)y0, fz = gz - (float)z0;
      int x1 = min(x0 + 1, 32), y1 = min(y0 + 1, 32), z1 = min(z0 + 1, 32);
      int zy00 = (z0 * LDIM + y0) * LDIM, zy01 = (z0 * LDIM + y1) * LDIM;
      int zy10 = (z1 * LDIM + y0) * LDIM, zy11 = (z1 * LDIM + y1) * LDIM;
      const float* L = lut;
      float c000 = L[(zy00 + x0) * 3 + q], c001 = L[(zy00 + x1) * 3 + q];
      float c010 = L[(zy01 + x0) * 3 + q], c011 = L[(zy01 + x1) * 3 + q];
      float c100 = L[(zy10 + x0) * 3 + q], c101 = L[(zy10 + x1) * 3 + q];
      float c110 = L[(zy11 + x0) * 3 + q], c111 = L[(zy11 + x1) * 3 + q];
      float c00 = c000 + fx * (c001 - c000);
      float c01 = c010 + fx * (c011 - c010);
      float c10 = c100 + fx * (c101 - c100);
      float c11 = c110 + fx * (c111 - c110);
      float ca  = c00 + fy * (c01 - c00);
      float cb2 = c10 + fy * (c11 - c10);
      float so  = ca + fz * (cb2 - ca);
      outB[q * HW + sp] = so * 2.f - 1.f + ov;
    }
  }
}

extern "C" void kernel_launch(void* const* d_in, const int* in_sizes, int n_in,
                              void* d_out, int out_size, void* d_ws, size_t ws_size,
                              hipStream_t stream) {
  const float* img = (const float*)d_in[0];
  const float* ctx = (const float*)d_in[1];
  const float* lut = (const float*)d_in[2];
  const float* W1  = (const float*)d_in[3];
  const float* b1  = (const float*)d_in[4];
  const float* W2  = (const float*)d_in[5];
  const float* b2  = (const float*)d_in[6];
  const float* W3  = (const float*)d_in[7];
  const float* b3  = (const float*)d_in[8];
  const float* osc = (const float*)d_in[9];
  float* out = (float*)d_out;
  // 1024 blocks x 1024 px; 512 threads (8 waves), 64 KB LDS -> 2 blocks/CU;
  // VGPR target <= 128 total -> 16 waves/CU
  local3dlut_kernel<<<dim3(1024), dim3(512), 0, stream>>>(
      img, ctx, lut, W1, b1, W2, b2, W3, b3, osc, out);
}